// Round 11
// baseline (135.523 us; speedup 1.0000x reference)
//
#include <hip/hip_runtime.h>
#include <math.h>

#define L_SEQ 1024
#define TOPK 6
#define RSTR 36     // row stride (floats): %4==0 (b128 align), %32==4 (banks)
#define PSTR 1156   // plane stride (floats): 32*36+4
#define NFBLK 2048  // one (b,h,e-octet) per block

// W32^m = e^{-2*pi*i*m/32}, compile-time constants
__device__ constexpr float TW32R[16] = {
  1.f, 0.98078528f, 0.92387953f, 0.83146961f, 0.70710678f, 0.55557023f,
  0.38268343f, 0.19509032f, 0.f, -0.19509032f, -0.38268343f, -0.55557023f,
  -0.70710678f, -0.83146961f, -0.92387953f, -0.98078528f};
__device__ constexpr float TW32I[16] = {
  0.f, -0.19509032f, -0.38268343f, -0.55557023f, -0.70710678f, -0.83146961f,
  -0.92387953f, -0.98078528f, -1.f, -0.98078528f, -0.92387953f, -0.83146961f,
  -0.70710678f, -0.55557023f, -0.38268343f, -0.19509032f};

// radix-2 DIT stage; m_==0 / m_==8 (W=1 / W=-i) fold at compile time.
#define FFTSTAGE(M, H, SH)                                                \
  _Pragma("unroll")                                                       \
  for (int k_ = 0; k_ < 32; k_ += (M)) {                                  \
    _Pragma("unroll")                                                     \
    for (int t_ = 0; t_ < (H); ++t_) {                                    \
      const int a_ = k_ + t_, b_ = a_ + (H);                              \
      const int m_ = t_ << (SH);                                          \
      float vr_, vi_;                                                     \
      if (m_ == 0)      { vr_ = zr[b_]; vi_ = zi[b_]; }                   \
      else if (m_ == 8) { vr_ = zi[b_]; vi_ = -zr[b_]; }                  \
      else {                                                              \
        vr_ = zr[b_] * TW32R[m_] - zi[b_] * TW32I[m_];                    \
        vi_ = zr[b_] * TW32I[m_] + zi[b_] * TW32R[m_];                    \
      }                                                                   \
      zr[b_] = zr[a_] - vr_; zi[b_] = zi[a_] - vi_;                       \
      zr[a_] += vr_;         zi[a_] += vi_;                               \
    }                                                                     \
  }

// ---------------------------------------------------------------------------
// Kernel 1: packed complex FFT + cross-spectrum partials (b128-vectorized).
// Block = one (b, h, e-octet): 8 seqs z = q + i*k. Four-step 1024-pt FFT.
// LDS layout: plane s (seq), element l at [s*PSTR + (l&31)*RSTR + (l>>5)].
// All contiguous LDS accesses are float4; bit-reversal is a compile-time
// register permutation. Pairing S[32k1+j] via __shfl in two k1-batches.
// Output partial[bid][v] in PERMUTED order v = j*32 + k1 (float4 stores);
// corr un-scrambles (true bin = ((v&31)<<5)|(v>>5)).
// ---------------------------------------------------------------------------
__global__ __launch_bounds__(256, 2) void fft_spec_kernel(
    const float* __restrict__ q, const float* __restrict__ k,
    float* __restrict__ partial)
{
  __shared__ float pr[8 * PSTR];   // 37 KB
  __shared__ float pim[8 * PSTR];  // 37 KB

  const int tid = threadIdx.x;
  const int bid = blockIdx.x;

  // work decode (round-10 proven): adjacent ids = octet pair of one 64-B
  // granule; bid&7 spreads XCDs.
  const int wq  = bid >> 3;
  const int xcd = bid & 7;
  const int octet = (wq & 1) | (((wq >> 1) & 3) << 1);
  const int h = (wq >> 3) & 7;
  const int b = (xcd << 2) | (wq >> 6);

  const float* qb = q + (size_t)b * 524288 + h * 64 + octet * 8;
  const float* kb = k + (size_t)b * 524288 + h * 64 + octet * 8;

  // ---- stage: float4 global loads, scalar LDS writes ----
  {
    const int ep = (tid & 1) * 4;
    const int lb = tid >> 1;                 // 0..127
    const int r  = lb & 31;
    const int cb = lb >> 5;                  // 0..3
    #pragma unroll
    for (int it = 0; it < 8; ++it) {
      const int l = it * 128 + lb;
      const float4 qv = *(const float4*)(qb + (size_t)l * 512 + ep);
      const float4 kv = *(const float4*)(kb + (size_t)l * 512 + ep);
      const int w = r * RSTR + cb + it * 4;
      pr [(ep + 0) * PSTR + w] = qv.x;
      pr [(ep + 1) * PSTR + w] = qv.y;
      pr [(ep + 2) * PSTR + w] = qv.z;
      pr [(ep + 3) * PSTR + w] = qv.w;
      pim[(ep + 0) * PSTR + w] = kv.x;
      pim[(ep + 1) * PSTR + w] = kv.y;
      pim[(ep + 2) * PSTR + w] = kv.z;
      pim[(ep + 3) * PSTR + w] = kv.w;
    }
  }
  __syncthreads();

  const int s = tid >> 5;     // sequence (0..7)
  const int i = tid & 31;     // lane within sequence
  constexpr int BR[32] = {0,16,8,24,4,20,12,28,2,18,10,26,6,22,14,30,
                          1,17,9,25,5,21,13,29,3,19,11,27,7,23,15,31};
  const float astep = (float)i * 6.13592315e-03f;   // 2*pi*i/1024
  float zr[32], zi[32];

  // ---- phase 1: b128 row read + static bit-reversal, FFT32, twiddle,
  //      b128 write back ----
  {
    const int rowbase = s * PSTR + i * RSTR;
    float lr[32], li[32];
    #pragma unroll
    for (int m = 0; m < 8; ++m) {
      const float4 vr = *(const float4*)(pr  + rowbase + m * 4);
      const float4 vi = *(const float4*)(pim + rowbase + m * 4);
      lr[m*4+0] = vr.x; lr[m*4+1] = vr.y; lr[m*4+2] = vr.z; lr[m*4+3] = vr.w;
      li[m*4+0] = vi.x; li[m*4+1] = vi.y; li[m*4+2] = vi.z; li[m*4+3] = vi.w;
    }
    #pragma unroll
    for (int p = 0; p < 32; ++p) { zr[p] = lr[BR[p]]; zi[p] = li[BR[p]]; }

    FFTSTAGE(2, 1, 4) FFTSTAGE(4, 2, 3) FFTSTAGE(8, 4, 2)
    FFTSTAGE(16, 8, 1) FFTSTAGE(32, 16, 0)

    #pragma unroll
    for (int k2 = 1; k2 < 32; ++k2) {      // k2==0: twiddle = 1
      float sa, ca;
      __sincosf(astep * (float)k2, &sa, &ca);
      const float nr = zr[k2] * ca + zi[k2] * sa;
      const float ni = zi[k2] * ca - zr[k2] * sa;
      zr[k2] = nr; zi[k2] = ni;
    }
    #pragma unroll
    for (int m = 0; m < 8; ++m) {
      *(float4*)(pr  + rowbase + m * 4) =
          make_float4(zr[m*4], zr[m*4+1], zr[m*4+2], zr[m*4+3]);
      *(float4*)(pim + rowbase + m * 4) =
          make_float4(zi[m*4], zi[m*4+1], zi[m*4+2], zi[m*4+3]);
    }
  }
  __syncthreads();

  // ---- phase 2: scalar column read (conflict-free) + static bit-rev ----
  const int j = i;
  {
    float lr[32], li[32];
    #pragma unroll
    for (int r = 0; r < 32; ++r) {
      lr[r] = pr [s * PSTR + r * RSTR + j];
      li[r] = pim[s * PSTR + r * RSTR + j];
    }
    #pragma unroll
    for (int p = 0; p < 32; ++p) { zr[p] = lr[BR[p]]; zi[p] = li[BR[p]]; }
  }
  __syncthreads();            // all column reads done before S overwrites

  FFTSTAGE(2, 1, 4) FFTSTAGE(4, 2, 3) FFTSTAGE(8, 4, 2)
  FFTSTAGE(16, 8, 1) FFTSTAGE(32, 16, 0)
  // lane j holds Z[32*k1 + j] in (zr[k1], zi[k1])

  // ---- pairing via shfl, two batches of 16, b128 row writes ----
  {
    const int t64 = tid & 63;
    const int pl = (t64 & 32) | ((32 - j) & 31);
    const int prow = s * PSTR + j * RSTR;
    float sr_[16], si_[16];

    #pragma unroll
    for (int k1 = 0; k1 < 16; ++k1) {      // uses partner regs 16..31
      float xr = __shfl(zr[31 - k1], pl, 64);
      float xi = __shfl(zi[31 - k1], pl, 64);
      if (j == 0) { xr = zr[(32 - k1) & 31]; xi = zi[(32 - k1) & 31]; }
      const float ar = zr[k1], ai = zi[k1];
      sr_[k1] = 0.5f  * (ar * xi + ai * xr);
      si_[k1] = 0.25f * (ar * ar + ai * ai - xr * xr - xi * xi);
    }
    #pragma unroll
    for (int m = 0; m < 4; ++m) {
      *(float4*)(pr  + prow + m * 4) =
          make_float4(sr_[m*4], sr_[m*4+1], sr_[m*4+2], sr_[m*4+3]);
      *(float4*)(pim + prow + m * 4) =
          make_float4(si_[m*4], si_[m*4+1], si_[m*4+2], si_[m*4+3]);
    }

    #pragma unroll
    for (int k1 = 16; k1 < 32; ++k1) {     // uses partner regs 0..15 (intact)
      float xr = __shfl(zr[31 - k1], pl, 64);
      float xi = __shfl(zi[31 - k1], pl, 64);
      if (j == 0) { xr = zr[(32 - k1) & 31]; xi = zi[(32 - k1) & 31]; }
      const float ar = zr[k1], ai = zi[k1];
      sr_[k1 - 16] = 0.5f  * (ar * xi + ai * xr);
      si_[k1 - 16] = 0.25f * (ar * ar + ai * ai - xr * xr - xi * xi);
    }
    #pragma unroll
    for (int m = 0; m < 4; ++m) {
      *(float4*)(pr  + prow + 16 + m * 4) =
          make_float4(sr_[m*4], sr_[m*4+1], sr_[m*4+2], sr_[m*4+3]);
      *(float4*)(pim + prow + 16 + m * 4) =
          make_float4(si_[m*4], si_[m*4+1], si_[m*4+2], si_[m*4+3]);
    }
  }
  __syncthreads();

  // ---- reduce 8 seqs, b128 reads, float4 stores (permuted order) ----
  {
    const int jj = tid >> 3;      // row j   (0..31)
    const int kq = tid & 7;       // col quad (0..7)
    float arx = 0.f, ary = 0.f, arz = 0.f, arw = 0.f;
    float aix = 0.f, aiy = 0.f, aiz = 0.f, aiw = 0.f;
    #pragma unroll
    for (int s2 = 0; s2 < 8; ++s2) {
      const float4 vr = *(const float4*)(pr  + s2 * PSTR + jj * RSTR + kq * 4);
      const float4 vi = *(const float4*)(pim + s2 * PSTR + jj * RSTR + kq * 4);
      arx += vr.x; ary += vr.y; arz += vr.z; arw += vr.w;
      aix += vi.x; aiy += vi.y; aiz += vi.z; aiw += vi.w;
    }
    const int v = jj * 32 + kq * 4;        // permuted bin base
    *(float4*)(partial + (size_t)bid * 2048 + v) =
        make_float4(arx, ary, arz, arw);
    *(float4*)(partial + (size_t)bid * 2048 + 1024 + v) =
        make_float4(aix, aiy, aiz, aiw);
  }
}

// ---------------------------------------------------------------------------
// Kernel 2: 4-way split reduce: S4[rc][v] = sum of 512 rows. grid 128.
// ---------------------------------------------------------------------------
__global__ __launch_bounds__(256) void spec_reduce(
    const float* __restrict__ partial, float* __restrict__ S4)
{
  const int t = threadIdx.x;
  const int b64 = t & 63, rq = t >> 6;
  const int vb = (blockIdx.x & 31) * 64;
  const int rc = blockIdx.x >> 5;          // 0..3
  const int v = vb + b64;
  float acc = 0.f;
  const int r0 = rc * 512 + rq * 128;
  for (int rr = r0; rr < r0 + 128; ++rr)
    acc += partial[(size_t)rr * 2048 + v];
  __shared__ float sm[4][65];
  sm[rq][b64] = acc;
  __syncthreads();
  if (t < 64)
    S4[(size_t)rc * 2048 + vb + t] =
        sm[0][t] + sm[1][t] + sm[2][t] + sm[3][t];
}

// ---------------------------------------------------------------------------
// Kernel 3: c[tau] = (1/2^24) * sum_v Re(S[v] e^{+2pi i jt(v) tau/1024}),
// jt(v) = ((v&31)<<5)|(v>>5)  (un-permute). grid 32.
// ---------------------------------------------------------------------------
__global__ __launch_bounds__(256) void corr_kernel(
    const float* __restrict__ S4, float* __restrict__ c)
{
  __shared__ float Sr[2048];
  __shared__ float sm[8][33];
  const int t = threadIdx.x;
  #pragma unroll
  for (int u = 0; u < 8; ++u) {
    const int v = u * 256 + t;
    Sr[v] = S4[v] + S4[2048 + v] + S4[4096 + v] + S4[6144 + v];
  }
  __syncthreads();

  const int tau = blockIdx.x * 32 + (t & 31);
  const int jc = t >> 5;
  float acc = 0.f;
  #pragma unroll 4
  for (int jj = 0; jj < 128; ++jj) {
    const int v = jc * 128 + jj;
    const int jt = ((v & 31) << 5) | (v >> 5);
    float s_, c_;
    __sincosf((float)((jt * tau) & 1023) * 6.13592315e-03f, &s_, &c_);
    acc += Sr[v] * c_ - Sr[1024 + v] * s_;
  }
  sm[jc][t & 31] = acc;
  __syncthreads();
  if (t < 32) {
    float r = 0.f;
    #pragma unroll
    for (int g = 0; g < 8; ++g) r += sm[g][t];
    c[blockIdx.x * 32 + t] = r * (1.0f / 16777216.0f);
  }
}

// ---------------------------------------------------------------------------
// Kernel 4: top-6 (desc, smaller-index tie-break) + softmax. 1 block.
// ---------------------------------------------------------------------------
__global__ __launch_bounds__(256) void topk_kernel(
    const float* __restrict__ c, int* __restrict__ idx_out,
    float* __restrict__ w_out)
{
  __shared__ float vals[L_SEQ];
  __shared__ float rv[256];
  __shared__ int ri[256];
  __shared__ float topv[TOPK];
  __shared__ int topi[TOPK];
  const int tid = threadIdx.x;
  for (int i = tid; i < L_SEQ; i += 256) vals[i] = c[i];
  __syncthreads();

  for (int kk = 0; kk < TOPK; ++kk) {
    float bv = -INFINITY;
    int bi = 1 << 30;
    for (int i = tid; i < L_SEQ; i += 256) {
      const float v = vals[i];
      if (v > bv || (v == bv && i < bi)) { bv = v; bi = i; }
    }
    rv[tid] = bv; ri[tid] = bi;
    __syncthreads();
    for (int off = 128; off > 0; off >>= 1) {
      if (tid < off) {
        const float v2 = rv[tid + off];
        const int i2 = ri[tid + off];
        if (v2 > rv[tid] || (v2 == rv[tid] && i2 < ri[tid])) {
          rv[tid] = v2; ri[tid] = i2;
        }
      }
      __syncthreads();
    }
    if (tid == 0) {
      topv[kk] = rv[0];
      topi[kk] = ri[0];
      vals[ri[0]] = -INFINITY;
    }
    __syncthreads();
  }

  if (tid == 0) {
    const float m = topv[0];
    float e[TOPK], sum = 0.f;
    for (int i = 0; i < TOPK; ++i) { e[i] = expf(topv[i] - m); sum += e[i]; }
    const float inv = 1.0f / sum;
    for (int i = 0; i < TOPK; ++i) { w_out[i] = e[i] * inv; idx_out[i] = topi[i]; }
  }
}

// ---------------------------------------------------------------------------
// Kernel 5: out[b,l,h,e] = sum_k w[k] * v[b,(l+idx[k])%L,h,e]
// ---------------------------------------------------------------------------
__global__ __launch_bounds__(256) void agg_kernel(
    const float* __restrict__ v, const int* __restrict__ idx,
    const float* __restrict__ w, float4* __restrict__ out)
{
  __shared__ int sidx[TOPK];
  __shared__ float sw[TOPK];
  if (threadIdx.x < TOPK) {
    sidx[threadIdx.x] = idx[threadIdx.x];
    sw[threadIdx.x] = w[threadIdx.x];
  }
  __syncthreads();

  const int i = blockIdx.x * 256 + threadIdx.x;   // 0 .. 2^22-1
  const int he4 = i & 127;
  const int l = (i >> 7) & (L_SEQ - 1);
  const int b = i >> 17;
  const float4* vb = (const float4*)v + (size_t)b * (L_SEQ * 128);

  float4 acc = make_float4(0.f, 0.f, 0.f, 0.f);
  #pragma unroll
  for (int kk = 0; kk < TOPK; ++kk) {
    const int src = (l + sidx[kk]) & (L_SEQ - 1);
    const float4 vv = vb[(size_t)src * 128 + he4];
    const float wk = sw[kk];
    acc.x += wk * vv.x; acc.y += wk * vv.y;
    acc.z += wk * vv.z; acc.w += wk * vv.w;
  }
  out[i] = acc;
}

// ---------------------------------------------------------------------------
extern "C" void kernel_launch(void* const* d_in, const int* in_sizes, int n_in,
                              void* d_out, int out_size, void* d_ws, size_t ws_size,
                              hipStream_t stream) {
  const float* q = (const float*)d_in[0];
  const float* k = (const float*)d_in[1];
  const float* v = (const float*)d_in[2];
  // d_in[3] = attn_mask (scalar 0) -- unused

  float* out = (float*)d_out;
  // scratch inside d_out (consumed before agg overwrites):
  //   partial: 2048 x 2048 floats (16 MB) at out[0]
  //   S4     : 4 x 2048 floats at out + 8M floats
  float* partial = out;
  float* S4 = out + (size_t)8388608;

  float* c    = (float*)d_ws;                          // 1024 floats
  int*   idxp = (int*)((char*)d_ws + 4096);            // 6 ints
  float* wp   = (float*)((char*)d_ws + 4096 + 64);     // 6 floats

  fft_spec_kernel<<<NFBLK, 256, 0, stream>>>(q, k, partial);
  spec_reduce<<<128, 256, 0, stream>>>(partial, S4);
  corr_kernel<<<32, 256, 0, stream>>>(S4, c);
  topk_kernel<<<1, 256, 0, stream>>>(c, idxp, wp);
  agg_kernel<<<(L_SEQ * 32 * 128) / 256, 256, 0, stream>>>(v, idxp, wp,
                                                           (float4*)out);
}